// Round 17
// baseline (4831.533 us; speedup 1.0000x reference)
//
#include <hip/hip_runtime.h>
#include <hip/hip_bf16.h>
#include <float.h>
#include <math.h>
#include <stdint.h>

#define NPTS 4096
#define KNN 32
#define BATCH 4
#define CPTS 64
#define EPS_BN 1e-5f
#define CLIP_EPS 1e-7f

static __device__ __forceinline__ unsigned short f2bf_bits(float x) {
    unsigned int u = __float_as_uint(x);
    unsigned int r = (u + 0x7fffu + ((u >> 16) & 1u)) >> 16;  // RNE
    return (unsigned short)r;
}

// ---------------------------------------------------------------- KNN ------
// One block per query point; 256 threads scan all 4096 candidates (16 each in
// registers), then 32 rounds of (min-value, lowest-index) extraction.
// Golden model, pinned by the 11-run failure matrix (site-invariance logic):
//   dot: dot-caused worst site fixed only by asc-FMA -> Eigen/oneDNN gemm
//        K-loop: fma(qz,z, fma(qy,y, qx*x))
//   d2 : residual moves with d2; ap/af excluded -> SIMD hsum tree of the
//        standalone (non-contracted) reduce: (x*x + z*z) + y*y
//   dist = (d2q + d2m) - 2*dot   (2*dot exact; one rounding per add/sub)
//   ties: LOWEST index (xla runtime_topk comparator: value desc, index asc)
__global__ __launch_bounds__(256) void knn_kernel(
    const float* __restrict__ xyz, int* __restrict__ ws_idx,
    float* __restrict__ out_idx)
{
#pragma clang fp contract(off)
    const int q = blockIdx.x;            // global query point
    const int b = q >> 12;               // / NPTS
    const int n = q & (NPTS - 1);
    const int tid = threadIdx.x;
    const float* xb = xyz + (size_t)b * NPTS * 3;

    const float qx = xb[n * 3 + 0], qy = xb[n * 3 + 1], qz = xb[n * 3 + 2];
    const float d2q = (qx * qx + qz * qz) + qy * qy;   // hsum tree

    float d[16];
#pragma unroll
    for (int i = 0; i < 16; ++i) {
        const int j = tid + (i << 8);
        const float x = xb[j * 3 + 0], y = xb[j * 3 + 1], z = xb[j * 3 + 2];
        const float d2m = (x * x + z * z) + y * y;           // hsum tree
        const float dt = fmaf(qz, z, fmaf(qy, y, qx * x));   // asc FMA chain
        d[i] = (d2q + d2m) - 2.0f * dt;
    }

    // per-thread local min with lowest-index tie-break
    float lv = FLT_MAX; int li = 0x7fffffff;
#pragma unroll
    for (int i = 0; i < 16; ++i) {
        if (d[i] < lv) { lv = d[i]; li = tid + (i << 8); }
    }

    __shared__ float s_v[2][4];
    __shared__ int   s_j[2][4];

    for (int r = 0; r < KNN; ++r) {
        float v = lv; int jj = li;
#pragma unroll
        for (int off = 32; off > 0; off >>= 1) {   // full wave64 reduce
            const float ov = __shfl_xor(v, off);
            const int   oj = __shfl_xor(jj, off);
            if (ov < v || (ov == v && oj < jj)) { v = ov; jj = oj; }
        }
        const int buf = r & 1;
        if ((tid & 63) == 0) { s_v[buf][tid >> 6] = v; s_j[buf][tid >> 6] = jj; }
        __syncthreads();
        float bv = s_v[buf][0]; int bj = s_j[buf][0];
#pragma unroll
        for (int w = 1; w < 4; ++w) {
            const float wv = s_v[buf][w]; const int wj = s_j[buf][w];
            if (wv < bv || (wv == bv && wj < bj)) { bv = wv; bj = wj; }
        }
        if (tid == 0) {
            ws_idx[(size_t)q * KNN + r] = bj;
            out_idx[(size_t)q * KNN + r] = (float)bj;   // float32 output
        }
        if ((bj & 255) == tid) {           // owner removes winner, rescans
#pragma unroll
            for (int i = 0; i < 16; ++i) if ((bj >> 8) == i) d[i] = FLT_MAX;
            lv = FLT_MAX; li = 0x7fffffff;
#pragma unroll
            for (int i = 0; i < 16; ++i) {
                if (d[i] < lv) { lv = d[i]; li = tid + (i << 8); }
            }
        }
    }
}

// ---------------------------------------------- fused geometry + MLP -------
// 256 threads = 8 points x 32 lanes. Lane k computes the geometry for
// neighbor k, ranks by dots (stable descending), scatters (dots, j) through
// LDS, then continues as the MLP thread for SORTED slot r=k: RI features and
// jo never touch global memory.
__global__ __launch_bounds__(256) void geomlp_kernel(
    const float* __restrict__ xyz, const float* __restrict__ norm,
    const int* __restrict__ ws_idx, const float* __restrict__ points,
    const float* __restrict__ p0w, const float* __restrict__ p0b,
    const float* __restrict__ p0g, const float* __restrict__ p0be,
    const float* __restrict__ p0m, const float* __restrict__ p0v,
    const float* __restrict__ p1w, const float* __restrict__ p1b,
    const float* __restrict__ p1g, const float* __restrict__ p1be,
    const float* __restrict__ p1m, const float* __restrict__ p1v,
    const float* __restrict__ m0w, const float* __restrict__ m0b,
    const float* __restrict__ m0g, const float* __restrict__ m0be,
    const float* __restrict__ m0m, const float* __restrict__ m0v,
    const float* __restrict__ m1w, const float* __restrict__ m1b,
    const float* __restrict__ m1g, const float* __restrict__ m1be,
    const float* __restrict__ m1m, const float* __restrict__ m1v,
    float* __restrict__ out)
{
#pragma clang fp contract(off)
    __shared__ float sd[8][32];
    __shared__ int   sjj[8][32];
    __shared__ unsigned short m0buf[256][136];  // 272B rows: 16B-aligned b128

    const int tid = threadIdx.x;
    const int slot = tid >> 5;           // 0..7 points per block
    const int k = tid & 31;
    const int p = blockIdx.x * 8 + slot; // global point
    const int b = p >> 12;
    const int n = p & (NPTS - 1);
    const float* xb = xyz + (size_t)b * NPTS * 3;
    const float* nb = norm + (size_t)b * NPTS * 3;

    const float sx = xb[n * 3 + 0], sy = xb[n * 3 + 1], sz = xb[n * 3 + 2];
    const float nx = nb[n * 3 + 0], ny = nb[n * 3 + 1], nz = nb[n * 3 + 2];

    const int j = ws_idx[(size_t)p * KNN + k];
    const float lx = xb[j * 3 + 0] - sx, ly = xb[j * 3 + 1] - sy, lz = xb[j * 3 + 2] - sz;
    const float dp = lx * nx + ly * ny + lz * nz;
    const float px = lx - dp * nx, py = ly - dp * ny, pz = lz - dp * nz;
    const float pl = sqrtf(px * px + py * py + pz * pz);
    const float pux = (pl > 0.f) ? px / pl : 0.f;
    const float puy = (pl > 0.f) ? py / pl : 0.f;
    const float puz = (pl > 0.f) ? pz / pl : 0.f;

    // argmax of pl over the 32-lane group, lowest-index tie-break (np.argmax)
    float mv = pl; int mk = k;
#pragma unroll
    for (int off = 16; off > 0; off >>= 1) {
        const float ov = __shfl_xor(mv, off, 32);
        const int   ok = __shfl_xor(mk, off, 32);
        if (ov > mv || (ov == mv && ok < mk)) { mv = ov; mk = ok; }
    }
    const float vrx = __shfl(pux, mk, 32);
    const float vry = __shfl(puy, mk, 32);
    const float vrz = __shfl(puz, mk, 32);

    float dots = pux * vrx + puy * vry + puz * vrz;
    const float cx = puy * vrz - puz * vry;
    const float cy = puz * vrx - pux * vrz;
    const float cz = pux * vry - puy * vrx;
    const float sdot = cx * nx + cy * ny + cz * nz;
    float sg = (sdot > 0.f) ? 1.f : ((sdot < 0.f) ? -1.f : 0.f);
    if (k == 0) sg = 1.f;
    dots = sg * dots - (1.f - sg);

    // stable descending rank (== stable argsort(-dots), lowest idx on ties)
    int rank = 0;
#pragma unroll
    for (int t = 0; t < 32; ++t) {
        const float dt = __shfl(dots, t, 32);
        if (dt > dots || (dt == dots && t < k)) ++rank;
    }

    sd[slot][rank] = dots;
    sjj[slot][rank] = j;
    __syncthreads();

    const int r = k;                      // lane now handles sorted slot r
    const float ds_ = sd[slot][r];
    const int jo = sjj[slot][r];
    const int rp = (r + 31) & 31;
    const float dsp = sd[slot][rp];
    const int jp = sjj[slot][rp];
    const float dlast = sd[slot][31];

    const float ax = xb[jo * 3 + 0] - sx, ay = xb[jo * 3 + 1] - sy, az = xb[jo * 3 + 2] - sz;
    const float len = sqrtf(ax * ax + ay * ay + az * az);
    const float ux = (len > 0.f) ? ax / len : 0.f;
    const float uy = (len > 0.f) ? ay / len : 0.f;
    const float uz = (len > 0.f) ? az / len : 0.f;
    const float gnx = nb[jo * 3 + 0], gny = nb[jo * 3 + 1], gnz = nb[jo * 3 + 2];
    const float bx_ = xb[jp * 3 + 0] - sx, by_ = xb[jp * 3 + 1] - sy, bz_ = xb[jp * 3 + 2] - sz;
    const float gpx = nb[jp * 3 + 0], gpy = nb[jp * 3 + 1], gpz = nb[jp * 3 + 2];

    const float a0 = ux * nx + uy * ny + uz * nz;
    const float a1 = ux * gnx + uy * gny + uz * gnz;
    float cn = gnx * nx + gny * ny + gnz * nz;
    cn = fminf(fmaxf(cn, -1.f + CLIP_EPS), 1.f - CLIP_EPS);
    float an = acosf(cn);
    an = (a0 < a1) ? an : -an;

    const float ivx = ax - bx_, ivy = ay - by_, ivz = az - bz_;
    const float ivl = sqrtf(ivx * ivx + ivy * ivy + ivz * ivz);
    const float iux = (ivl > 0.f) ? ivx / ivl : 0.f;
    const float iuy = (ivl > 0.f) ? ivy / ivl : 0.f;
    const float iuz = (ivl > 0.f) ? ivz / ivl : 0.f;
    const float ia0 = iux * gnx + iuy * gny + iuz * gnz;
    const float ia1 = iux * gpx + iuy * gpy + iuz * gpz;
    float cg = gnx * gpx + gny * gpy + gnz * gpz;
    cg = fminf(fmaxf(cg, -1.f + CLIP_EPS), 1.f - CLIP_EPS);
    float ia2 = acosf(cg);
    ia2 = (ia0 < ia1) ? ia2 : -ia2;

    const float pif = (r == 0) ? (-3.0f - dlast) : (ds_ - dsp);

    float f[8];
    f[0] = len; f[1] = pif; f[2] = a0; f[3] = a1;
    f[4] = an;  f[5] = ia0; f[6] = ia1; f[7] = ia2;

    // ----------------------------- MLP: p0 -> p1 -> [.,gp] -> m0 -> m1 -----
    float h1[32];
#pragma unroll
    for (int o = 0; o < 32; ++o) {
        const float A = p0g[o] / sqrtf(p0v[o] + EPS_BN);
        const float C = (p0b[o] - p0m[o]) * A + p0be[o];
        float acc = 0.f;
#pragma unroll
        for (int c = 0; c < 8; ++c) acc = fmaf(f[c], p0w[o * 8 + c], acc);
        h1[o] = fmaxf(fmaf(acc, A, C), 0.f);
    }

    float h2[64];
#pragma unroll
    for (int o = 0; o < 64; ++o) {
        const float A = p1g[o] / sqrtf(p1v[o] + EPS_BN);
        const float C = (p1b[o] - p1m[o]) * A + p1be[o];
        float acc = 0.f;
#pragma unroll
        for (int c = 0; c < 32; ++c) acc = fmaf(h1[c], p1w[o * 32 + c], acc);
        h2[o] = fmaxf(fmaf(acc, A, C), 0.f);
    }

    float gp[64];
    {
        const float4* g4 = reinterpret_cast<const float4*>(points + ((size_t)b * NPTS + jo) * CPTS);
#pragma unroll
        for (int i = 0; i < 16; ++i) {
            const float4 v = g4[i];
            gp[4 * i + 0] = v.x; gp[4 * i + 1] = v.y;
            gp[4 * i + 2] = v.z; gp[4 * i + 3] = v.w;
        }
    }

    // m0: 128 outputs in 8 chunks of 16, result to bf16 LDS (own row only)
    for (int oc = 0; oc < 8; ++oc) {
        float acc[16];
#pragma unroll
        for (int jq = 0; jq < 16; ++jq) acc[jq] = 0.f;
#pragma unroll
        for (int c = 0; c < 64; ++c) {
            const float hv = h2[c];
#pragma unroll
            for (int jq = 0; jq < 16; ++jq)
                acc[jq] = fmaf(hv, m0w[(oc * 16 + jq) * 128 + c], acc[jq]);
        }
#pragma unroll
        for (int c = 0; c < 64; ++c) {
            const float gv = gp[c];
#pragma unroll
            for (int jq = 0; jq < 16; ++jq)
                acc[jq] = fmaf(gv, m0w[(oc * 16 + jq) * 128 + 64 + c], acc[jq]);
        }
#pragma unroll
        for (int jq = 0; jq < 16; ++jq) {
            const int o = oc * 16 + jq;
            const float A = m0g[o] / sqrtf(m0v[o] + EPS_BN);
            const float C = (m0b[o] - m0m[o]) * A + m0be[o];
            m0buf[tid][o] = f2bf_bits(fmaxf(fmaf(acc[jq], A, C), 0.f));
        }
    }

    // m1 + mean over k (32-lane group); own-row LDS reads, no barrier needed
    float* ob = out + (size_t)p * 256;
    for (int oc = 0; oc < 16; ++oc) {
        float acc[16];
#pragma unroll
        for (int jq = 0; jq < 16; ++jq) acc[jq] = 0.f;
#pragma unroll
        for (int c8 = 0; c8 < 16; ++c8) {
            const uint4 raw = *reinterpret_cast<const uint4*>(&m0buf[tid][c8 * 8]);
            float v[8];
            v[0] = __uint_as_float(raw.x << 16);
            v[1] = __uint_as_float(raw.x & 0xffff0000u);
            v[2] = __uint_as_float(raw.y << 16);
            v[3] = __uint_as_float(raw.y & 0xffff0000u);
            v[4] = __uint_as_float(raw.z << 16);
            v[5] = __uint_as_float(raw.z & 0xffff0000u);
            v[6] = __uint_as_float(raw.w << 16);
            v[7] = __uint_as_float(raw.w & 0xffff0000u);
#pragma unroll
            for (int jj = 0; jj < 8; ++jj) {
#pragma unroll
                for (int jq = 0; jq < 16; ++jq)
                    acc[jq] = fmaf(v[jj], m1w[(oc * 16 + jq) * 128 + c8 * 8 + jj], acc[jq]);
            }
        }
#pragma unroll
        for (int jq = 0; jq < 16; ++jq) {
            const int o = oc * 16 + jq;
            const float A = m1g[o] / sqrtf(m1v[o] + EPS_BN);
            const float C = (m1b[o] - m1m[o]) * A + m1be[o];
            float y = fmaxf(fmaf(acc[jq], A, C), 0.f);
#pragma unroll
            for (int off = 16; off > 0; off >>= 1) y += __shfl_xor(y, off, 32);
            if (k == 0) ob[o] = y * (1.f / 32.f);   // float32 output
        }
    }
}

// ----------------------------------------------------------------- launch --
extern "C" void kernel_launch(void* const* d_in, const int* in_sizes, int n_in,
                              void* d_out, int out_size, void* d_ws, size_t ws_size,
                              hipStream_t stream) {
    const float* xyz    = (const float*)d_in[0];
    const float* norm   = (const float*)d_in[1];
    const float* points = (const float*)d_in[2];
    const float* p0w = (const float*)d_in[3];
    const float* p0b = (const float*)d_in[4];
    const float* p0g = (const float*)d_in[5];
    const float* p0be = (const float*)d_in[6];
    const float* p0m = (const float*)d_in[7];
    const float* p0v = (const float*)d_in[8];
    const float* p1w = (const float*)d_in[9];
    const float* p1b = (const float*)d_in[10];
    const float* p1g = (const float*)d_in[11];
    const float* p1be = (const float*)d_in[12];
    const float* p1m = (const float*)d_in[13];
    const float* p1v = (const float*)d_in[14];
    const float* m0w = (const float*)d_in[15];
    const float* m0b = (const float*)d_in[16];
    const float* m0g = (const float*)d_in[17];
    const float* m0be = (const float*)d_in[18];
    const float* m0m = (const float*)d_in[19];
    const float* m0v = (const float*)d_in[20];
    const float* m1w = (const float*)d_in[21];
    const float* m1b = (const float*)d_in[22];
    const float* m1g = (const float*)d_in[23];
    const float* m1be = (const float*)d_in[24];
    const float* m1m = (const float*)d_in[25];
    const float* m1v = (const float*)d_in[26];

    int* ws_idx = (int*)d_ws;                          // 2 MB only

    float* out     = (float*)d_out;                    // (B,N,256) float32
    float* out_idx = out + (size_t)BATCH * NPTS * 256; // (B,N,32)  float32

    knn_kernel<<<BATCH * NPTS, 256, 0, stream>>>(xyz, ws_idx, out_idx);
    geomlp_kernel<<<BATCH * NPTS / 8, 256, 0, stream>>>(
        xyz, norm, ws_idx, points,
        p0w, p0b, p0g, p0be, p0m, p0v,
        p1w, p1b, p1g, p1be, p1m, p1v,
        m0w, m0b, m0g, m0be, m0m, m0v,
        m1w, m1b, m1g, m1be, m1m, m1v,
        out);
}

// Round 18
// 827.797 us; speedup vs baseline: 5.8366x; 5.8366x over previous
//
#include <hip/hip_runtime.h>
#include <hip/hip_bf16.h>
#include <float.h>
#include <math.h>
#include <stdint.h>

#define NPTS 4096
#define KNN 32
#define BATCH 4
#define CPTS 64
#define EPS_BN 1e-5f
#define CLIP_EPS 1e-7f

typedef short short8v __attribute__((ext_vector_type(8)));
typedef float float4v __attribute__((ext_vector_type(4)));

static __device__ __forceinline__ unsigned short f2bf_bits(float x) {
    unsigned int u = __float_as_uint(x);
    unsigned int r = (u + 0x7fffu + ((u >> 16) & 1u)) >> 16;  // RNE
    return (unsigned short)r;
}
static __device__ __forceinline__ unsigned pack2(float a, float b) {
    return (unsigned)f2bf_bits(a) | ((unsigned)f2bf_bits(b) << 16);
}

// ---------------------------------------------------------------- KNN ------
// (verbatim from the passing round-17 kernel — correctness-critical)
__global__ __launch_bounds__(256) void knn_kernel(
    const float* __restrict__ xyz, int* __restrict__ ws_idx,
    float* __restrict__ out_idx)
{
#pragma clang fp contract(off)
    const int q = blockIdx.x;
    const int b = q >> 12;
    const int n = q & (NPTS - 1);
    const int tid = threadIdx.x;
    const float* xb = xyz + (size_t)b * NPTS * 3;

    const float qx = xb[n * 3 + 0], qy = xb[n * 3 + 1], qz = xb[n * 3 + 2];
    const float d2q = (qx * qx + qz * qz) + qy * qy;   // hsum tree

    float d[16];
#pragma unroll
    for (int i = 0; i < 16; ++i) {
        const int j = tid + (i << 8);
        const float x = xb[j * 3 + 0], y = xb[j * 3 + 1], z = xb[j * 3 + 2];
        const float d2m = (x * x + z * z) + y * y;           // hsum tree
        const float dt = fmaf(qz, z, fmaf(qy, y, qx * x));   // asc FMA chain
        d[i] = (d2q + d2m) - 2.0f * dt;
    }

    float lv = FLT_MAX; int li = 0x7fffffff;
#pragma unroll
    for (int i = 0; i < 16; ++i) {
        if (d[i] < lv) { lv = d[i]; li = tid + (i << 8); }
    }

    __shared__ float s_v[2][4];
    __shared__ int   s_j[2][4];

    for (int r = 0; r < KNN; ++r) {
        float v = lv; int jj = li;
#pragma unroll
        for (int off = 32; off > 0; off >>= 1) {
            const float ov = __shfl_xor(v, off);
            const int   oj = __shfl_xor(jj, off);
            if (ov < v || (ov == v && oj < jj)) { v = ov; jj = oj; }
        }
        const int buf = r & 1;
        if ((tid & 63) == 0) { s_v[buf][tid >> 6] = v; s_j[buf][tid >> 6] = jj; }
        __syncthreads();
        float bv = s_v[buf][0]; int bj = s_j[buf][0];
#pragma unroll
        for (int w = 1; w < 4; ++w) {
            const float wv = s_v[buf][w]; const int wj = s_j[buf][w];
            if (wv < bv || (wv == bv && wj < bj)) { bv = wv; bj = wj; }
        }
        if (tid == 0) {
            ws_idx[(size_t)q * KNN + r] = bj;
            out_idx[(size_t)q * KNN + r] = (float)bj;
        }
        if ((bj & 255) == tid) {
#pragma unroll
            for (int i = 0; i < 16; ++i) if ((bj >> 8) == i) d[i] = FLT_MAX;
            lv = FLT_MAX; li = 0x7fffffff;
#pragma unroll
            for (int i = 0; i < 16; ++i) {
                if (d[i] < lv) { lv = d[i]; li = tid + (i << 8); }
            }
        }
    }
}

// -------------------------------------------------- weight precvt ----------
// Folds the BN scale A = g/sqrt(v+eps) into bf16 weights; emits bias C.
__global__ __launch_bounds__(256) void precvt_kernel(
    const float* __restrict__ w, const float* __restrict__ g,
    const float* __restrict__ v, const float* __restrict__ bb,
    const float* __restrict__ m, const float* __restrict__ be,
    int CO, int CI, unsigned short* __restrict__ wb, float* __restrict__ cb)
{
    const int stride = gridDim.x * blockDim.x;
    const int t0 = blockIdx.x * blockDim.x + threadIdx.x;
    for (int o = t0; o < CO; o += stride) {
        const float A = g[o] / sqrtf(v[o] + EPS_BN);
        cb[o] = (bb[o] - m[o]) * A + be[o];
    }
    for (int idx = t0; idx < CO * CI; idx += stride) {
        const int o = idx / CI;
        const float A = g[o] / sqrtf(v[o] + EPS_BN);
        wb[idx] = f2bf_bits(w[idx] * A);
    }
}

// --------------------------- fused geometry + p0/p1 + MFMA m0/m1 -----------
// 256 threads = 8 points x 32 lanes. Geometry identical to the verified
// kernel; X = [h2|gp] goes to swizzled bf16 LDS; each wave (2 points, 64
// rows) runs m0 then m1 as 16x16x32 bf16 MFMA GEMMs with BN folded into the
// weights; mean over k fused into the m1 epilogue.
__global__ __launch_bounds__(256) void geomlp_kernel(
    const float* __restrict__ xyz, const float* __restrict__ norm,
    const int* __restrict__ ws_idx, const float* __restrict__ points,
    const float* __restrict__ p0w, const float* __restrict__ p0b,
    const float* __restrict__ p0g, const float* __restrict__ p0be,
    const float* __restrict__ p0m, const float* __restrict__ p0v,
    const float* __restrict__ p1w, const float* __restrict__ p1b,
    const float* __restrict__ p1g, const float* __restrict__ p1be,
    const float* __restrict__ p1m, const float* __restrict__ p1v,
    const unsigned short* __restrict__ w0b, const float* __restrict__ c0,
    const unsigned short* __restrict__ w1b, const float* __restrict__ c1,
    float* __restrict__ out)
{
#pragma clang fp contract(off)
    __shared__ unsigned short Xs[256 * 128];   // 64 KB; swizzled rows of 256B
    // sd/sjj alias the head of Xs (all reads complete before X is written)
    float* sd  = reinterpret_cast<float*>(Xs);          // [8][32]
    int*   sjj = reinterpret_cast<int*>(Xs) + 256;      // [8][32]

    const int tid = threadIdx.x;
    const int slot = tid >> 5;
    const int k = tid & 31;
    const int p = blockIdx.x * 8 + slot;
    const int b = p >> 12;
    const int n = p & (NPTS - 1);
    const float* xb = xyz + (size_t)b * NPTS * 3;
    const float* nb = norm + (size_t)b * NPTS * 3;

    const float sx = xb[n * 3 + 0], sy = xb[n * 3 + 1], sz = xb[n * 3 + 2];
    const float nx = nb[n * 3 + 0], ny = nb[n * 3 + 1], nz = nb[n * 3 + 2];

    const int j = ws_idx[(size_t)p * KNN + k];
    const float lx = xb[j * 3 + 0] - sx, ly = xb[j * 3 + 1] - sy, lz = xb[j * 3 + 2] - sz;
    const float dp = lx * nx + ly * ny + lz * nz;
    const float px = lx - dp * nx, py = ly - dp * ny, pz = lz - dp * nz;
    const float pl = sqrtf(px * px + py * py + pz * pz);
    const float pux = (pl > 0.f) ? px / pl : 0.f;
    const float puy = (pl > 0.f) ? py / pl : 0.f;
    const float puz = (pl > 0.f) ? pz / pl : 0.f;

    float mv = pl; int mk = k;
#pragma unroll
    for (int off = 16; off > 0; off >>= 1) {
        const float ov = __shfl_xor(mv, off, 32);
        const int   ok = __shfl_xor(mk, off, 32);
        if (ov > mv || (ov == mv && ok < mk)) { mv = ov; mk = ok; }
    }
    const float vrx = __shfl(pux, mk, 32);
    const float vry = __shfl(puy, mk, 32);
    const float vrz = __shfl(puz, mk, 32);

    float dots = pux * vrx + puy * vry + puz * vrz;
    const float cx = puy * vrz - puz * vry;
    const float cy = puz * vrx - pux * vrz;
    const float cz = pux * vry - puy * vrx;
    const float sdot = cx * nx + cy * ny + cz * nz;
    float sg = (sdot > 0.f) ? 1.f : ((sdot < 0.f) ? -1.f : 0.f);
    if (k == 0) sg = 1.f;
    dots = sg * dots - (1.f - sg);

    int rank = 0;
#pragma unroll
    for (int t = 0; t < 32; ++t) {
        const float dt = __shfl(dots, t, 32);
        if (dt > dots || (dt == dots && t < k)) ++rank;
    }

    sd[slot * 32 + rank] = dots;
    sjj[slot * 32 + rank] = j;
    __syncthreads();

    const int r = k;
    const float ds_ = sd[slot * 32 + r];
    const int jo = sjj[slot * 32 + r];
    const int rp = (r + 31) & 31;
    const float dsp = sd[slot * 32 + rp];
    const int jp = sjj[slot * 32 + rp];
    const float dlast = sd[slot * 32 + 31];
    __syncthreads();   // all sd/sjj reads done before X overwrites the alias

    const float ax = xb[jo * 3 + 0] - sx, ay = xb[jo * 3 + 1] - sy, az = xb[jo * 3 + 2] - sz;
    const float len = sqrtf(ax * ax + ay * ay + az * az);
    const float ux = (len > 0.f) ? ax / len : 0.f;
    const float uy = (len > 0.f) ? ay / len : 0.f;
    const float uz = (len > 0.f) ? az / len : 0.f;
    const float gnx = nb[jo * 3 + 0], gny = nb[jo * 3 + 1], gnz = nb[jo * 3 + 2];
    const float bx_ = xb[jp * 3 + 0] - sx, by_ = xb[jp * 3 + 1] - sy, bz_ = xb[jp * 3 + 2] - sz;
    const float gpx = nb[jp * 3 + 0], gpy = nb[jp * 3 + 1], gpz = nb[jp * 3 + 2];

    const float a0 = ux * nx + uy * ny + uz * nz;
    const float a1 = ux * gnx + uy * gny + uz * gnz;
    float cn = gnx * nx + gny * ny + gnz * nz;
    cn = fminf(fmaxf(cn, -1.f + CLIP_EPS), 1.f - CLIP_EPS);
    float an = acosf(cn);
    an = (a0 < a1) ? an : -an;

    const float ivx = ax - bx_, ivy = ay - by_, ivz = az - bz_;
    const float ivl = sqrtf(ivx * ivx + ivy * ivy + ivz * ivz);
    const float iux = (ivl > 0.f) ? ivx / ivl : 0.f;
    const float iuy = (ivl > 0.f) ? ivy / ivl : 0.f;
    const float iuz = (ivl > 0.f) ? ivz / ivl : 0.f;
    const float ia0 = iux * gnx + iuy * gny + iuz * gnz;
    const float ia1 = iux * gpx + iuy * gpy + iuz * gpz;
    float cg = gnx * gpx + gny * gpy + gnz * gpz;
    cg = fminf(fmaxf(cg, -1.f + CLIP_EPS), 1.f - CLIP_EPS);
    float ia2 = acosf(cg);
    ia2 = (ia0 < ia1) ? ia2 : -ia2;

    const float pif = (r == 0) ? (-3.0f - dlast) : (ds_ - dsp);

    float f[8];
    f[0] = len; f[1] = pif; f[2] = a0; f[3] = a1;
    f[4] = an;  f[5] = ia0; f[6] = ia1; f[7] = ia2;

    // p0 -> h1 (fp32, exact as before)
    float h1[32];
#pragma unroll
    for (int o = 0; o < 32; ++o) {
        const float A = p0g[o] / sqrtf(p0v[o] + EPS_BN);
        const float C = (p0b[o] - p0m[o]) * A + p0be[o];
        float acc = 0.f;
#pragma unroll
        for (int c = 0; c < 8; ++c) acc = fmaf(f[c], p0w[o * 8 + c], acc);
        h1[o] = fmaxf(fmaf(acc, A, C), 0.f);
    }
    // p1 -> h2
    float h2[64];
#pragma unroll
    for (int o = 0; o < 64; ++o) {
        const float A = p1g[o] / sqrtf(p1v[o] + EPS_BN);
        const float C = (p1b[o] - p1m[o]) * A + p1be[o];
        float acc = 0.f;
#pragma unroll
        for (int c = 0; c < 32; ++c) acc = fmaf(h1[c], p1w[o * 32 + c], acc);
        h2[o] = fmaxf(fmaf(acc, A, C), 0.f);
    }

    // ---- write X row (row=tid): cols 0-63 = h2, 64-127 = gp, bf16, swizzled
    {
        const int row = tid;
        unsigned short* base = Xs + row * 128;
        const int rs = row & 15;
#pragma unroll
        for (int c = 0; c < 8; ++c) {
            uint4 u;
            u.x = pack2(h2[c * 8 + 0], h2[c * 8 + 1]);
            u.y = pack2(h2[c * 8 + 2], h2[c * 8 + 3]);
            u.z = pack2(h2[c * 8 + 4], h2[c * 8 + 5]);
            u.w = pack2(h2[c * 8 + 6], h2[c * 8 + 7]);
            *reinterpret_cast<uint4*>(base + ((c ^ rs) << 3)) = u;
        }
        const float4* g4 = reinterpret_cast<const float4*>(
            points + ((size_t)b * NPTS + jo) * CPTS);
#pragma unroll
        for (int c = 0; c < 8; ++c) {
            const float4 v0 = g4[c * 2], v1 = g4[c * 2 + 1];
            uint4 u;
            u.x = pack2(v0.x, v0.y);
            u.y = pack2(v0.z, v0.w);
            u.z = pack2(v1.x, v1.y);
            u.w = pack2(v1.z, v1.w);
            *reinterpret_cast<uint4*>(base + (((c + 8) ^ rs) << 3)) = u;
        }
    }
    __syncthreads();

    // =================== MFMA GEMM phase (wave = 2 points = 64 rows) =======
    const int w = tid >> 6;
    const int lane = tid & 63;
    const int lrow = lane & 15;       // A row / B col / D col
    const int lk = lane >> 4;         // k-group
    const int wrow = w * 64;

    // ---- m0: Y0[64][128] = relu(X[64][128] . W0'[128][128]^T + C0)
    unsigned y0h[2][16][2];           // held packed bf16 (static-indexed)
#pragma unroll
    for (int nh = 0; nh < 2; ++nh) {
        float4v acc[4][4];
#pragma unroll
        for (int mt = 0; mt < 4; ++mt)
#pragma unroll
            for (int nt = 0; nt < 4; ++nt) acc[mt][nt] = (float4v)0.f;
#pragma unroll
        for (int kk = 0; kk < 4; ++kk) {
            short8v a[4];
#pragma unroll
            for (int mt = 0; mt < 4; ++mt) {
                const int row = wrow + mt * 16 + lrow;
                const int ch = (kk * 4 + lk) ^ (row & 15);
                const uint4 u = *reinterpret_cast<const uint4*>(Xs + row * 128 + (ch << 3));
                union { uint4 u; short8v s; } cv; cv.u = u;
                a[mt] = cv.s;
            }
#pragma unroll
            for (int nt = 0; nt < 4; ++nt) {
                const int nn = nh * 64 + nt * 16 + lrow;
                const uint4 ub = *reinterpret_cast<const uint4*>(w0b + nn * 128 + kk * 32 + lk * 8);
                union { uint4 u; short8v s; } cb; cb.u = ub;
                const short8v bf = cb.s;
#pragma unroll
                for (int mt = 0; mt < 4; ++mt)
                    acc[mt][nt] = __builtin_amdgcn_mfma_f32_16x16x32_bf16(a[mt], bf, acc[mt][nt], 0, 0, 0);
            }
        }
#pragma unroll
        for (int mt = 0; mt < 4; ++mt)
#pragma unroll
            for (int nt = 0; nt < 4; ++nt) {
                const int col = nh * 64 + nt * 16 + lrow;
                const float cc = c0[col];
                const float e0 = fmaxf(acc[mt][nt][0] + cc, 0.f);
                const float e1 = fmaxf(acc[mt][nt][1] + cc, 0.f);
                const float e2 = fmaxf(acc[mt][nt][2] + cc, 0.f);
                const float e3 = fmaxf(acc[mt][nt][3] + cc, 0.f);
                y0h[nh][mt * 4 + nt][0] = pack2(e0, e1);
                y0h[nh][mt * 4 + nt][1] = pack2(e2, e3);
            }
    }
    // X (this wave's rows) now dead -> write Y0 over it (swizzled, b16 each)
#pragma unroll
    for (int nh = 0; nh < 2; ++nh)
#pragma unroll
        for (int mt = 0; mt < 4; ++mt)
#pragma unroll
            for (int nt = 0; nt < 4; ++nt) {
                const int col = nh * 64 + nt * 16 + lrow;
                const int r0 = wrow + mt * 16 + lk * 4;
                const unsigned u0 = y0h[nh][mt * 4 + nt][0];
                const unsigned u1 = y0h[nh][mt * 4 + nt][1];
#pragma unroll
                for (int rr = 0; rr < 4; ++rr) {
                    const int row = r0 + rr;
                    const unsigned val = (rr < 2) ? (u0 >> (16 * rr)) : (u1 >> (16 * (rr - 2)));
                    Xs[row * 128 + ((((col >> 3) ^ (row & 15))) << 3) + (col & 7)] =
                        (unsigned short)val;
                }
            }

    // ---- m1: out[p][0..255] = mean_rows relu(Y0 . W1'^T + C1)
    const int p0_ = blockIdx.x * 8 + 2 * w;
#pragma unroll
    for (int ch4 = 0; ch4 < 4; ++ch4) {
        float4v acc[4][4];
#pragma unroll
        for (int mt = 0; mt < 4; ++mt)
#pragma unroll
            for (int nt = 0; nt < 4; ++nt) acc[mt][nt] = (float4v)0.f;
#pragma unroll
        for (int kk = 0; kk < 4; ++kk) {
            short8v a[4];
#pragma unroll
            for (int mt = 0; mt < 4; ++mt) {
                const int row = wrow + mt * 16 + lrow;
                const int ch = (kk * 4 + lk) ^ (row & 15);
                const uint4 u = *reinterpret_cast<const uint4*>(Xs + row * 128 + (ch << 3));
                union { uint4 u; short8v s; } cv; cv.u = u;
                a[mt] = cv.s;
            }
#pragma unroll
            for (int nt = 0; nt < 4; ++nt) {
                const int nn = ch4 * 64 + nt * 16 + lrow;
                const uint4 ub = *reinterpret_cast<const uint4*>(w1b + nn * 128 + kk * 32 + lk * 8);
                union { uint4 u; short8v s; } cb; cb.u = ub;
                const short8v bf = cb.s;
#pragma unroll
                for (int mt = 0; mt < 4; ++mt)
                    acc[mt][nt] = __builtin_amdgcn_mfma_f32_16x16x32_bf16(a[mt], bf, acc[mt][nt], 0, 0, 0);
            }
        }
#pragma unroll
        for (int nt = 0; nt < 4; ++nt) {
            const int col = ch4 * 64 + nt * 16 + lrow;
            const float cc = c1[col];
            float s0 = 0.f, s1 = 0.f;
#pragma unroll
            for (int rr = 0; rr < 4; ++rr) {
                s0 += fmaxf(acc[0][nt][rr] + cc, 0.f) + fmaxf(acc[1][nt][rr] + cc, 0.f);
                s1 += fmaxf(acc[2][nt][rr] + cc, 0.f) + fmaxf(acc[3][nt][rr] + cc, 0.f);
            }
            s0 += __shfl_xor(s0, 16); s0 += __shfl_xor(s0, 32);
            s1 += __shfl_xor(s1, 16); s1 += __shfl_xor(s1, 32);
            if (lane < 16) {
                out[(size_t)(p0_ + 0) * 256 + col] = s0 * (1.f / 32.f);
                out[(size_t)(p0_ + 1) * 256 + col] = s1 * (1.f / 32.f);
            }
        }
    }
}

// ----------------------------------------------------------------- launch --
extern "C" void kernel_launch(void* const* d_in, const int* in_sizes, int n_in,
                              void* d_out, int out_size, void* d_ws, size_t ws_size,
                              hipStream_t stream) {
    const float* xyz    = (const float*)d_in[0];
    const float* norm   = (const float*)d_in[1];
    const float* points = (const float*)d_in[2];
    const float* p0w = (const float*)d_in[3];
    const float* p0b = (const float*)d_in[4];
    const float* p0g = (const float*)d_in[5];
    const float* p0be = (const float*)d_in[6];
    const float* p0m = (const float*)d_in[7];
    const float* p0v = (const float*)d_in[8];
    const float* p1w = (const float*)d_in[9];
    const float* p1b = (const float*)d_in[10];
    const float* p1g = (const float*)d_in[11];
    const float* p1be = (const float*)d_in[12];
    const float* p1m = (const float*)d_in[13];
    const float* p1v = (const float*)d_in[14];
    const float* m0w = (const float*)d_in[15];
    const float* m0b = (const float*)d_in[16];
    const float* m0g = (const float*)d_in[17];
    const float* m0be = (const float*)d_in[18];
    const float* m0m = (const float*)d_in[19];
    const float* m0v = (const float*)d_in[20];
    const float* m1w = (const float*)d_in[21];
    const float* m1b = (const float*)d_in[22];
    const float* m1g = (const float*)d_in[23];
    const float* m1be = (const float*)d_in[24];
    const float* m1m = (const float*)d_in[25];
    const float* m1v = (const float*)d_in[26];

    char* wsb = (char*)d_ws;
    int*            ws_idx = (int*)wsb;                          // 2 MB
    unsigned short* w0b    = (unsigned short*)(wsb + 2097152);   // 32 KB
    float*          c0     = (float*)(wsb + 2129920);            // 512 B
    unsigned short* w1b    = (unsigned short*)(wsb + 2130432);   // 64 KB
    float*          c1     = (float*)(wsb + 2195968);            // 1 KB

    float* out     = (float*)d_out;                    // (B,N,256) float32
    float* out_idx = out + (size_t)BATCH * NPTS * 256; // (B,N,32)  float32

    precvt_kernel<<<64, 256, 0, stream>>>(m0w, m0g, m0v, m0b, m0m, m0be,
                                          128, 128, w0b, c0);
    precvt_kernel<<<64, 256, 0, stream>>>(m1w, m1g, m1v, m1b, m1m, m1be,
                                          256, 128, w1b, c1);
    knn_kernel<<<BATCH * NPTS, 256, 0, stream>>>(xyz, ws_idx, out_idx);
    geomlp_kernel<<<BATCH * NPTS / 8, 256, 0, stream>>>(
        xyz, norm, ws_idx, points,
        p0w, p0b, p0g, p0be, p0m, p0v,
        p1w, p1b, p1g, p1be, p1m, p1v,
        w0b, c0, w1b, c1,
        out);
}